// Round 1
// baseline (4634.266 us; speedup 1.0000x reference)
//
#include <hip/hip_runtime.h>

// ---------------------------------------------------------------------------
// Problem dims (fixed)
// ---------------------------------------------------------------------------
// B=4 T0=256 T1=768 T=1024 D=2048 N=8 K=1 H=256 F=16384, G=8
// Segment 0 rows: B*T0 = 1024.  Segment 1 rows: B*T1 = 3072.  Total 4096.

typedef __bf16 bf16_8 __attribute__((ext_vector_type(8)));
typedef float  f32_4  __attribute__((ext_vector_type(4)));

// ---------------------------------------------------------------------------
// Workspace layout (float offsets). Reuse: logits lives in gate region
// (dead before MLP); hidden reuses pre (dead after QKV GEMMs).
// ---------------------------------------------------------------------------
constexpr long long O_PRE   = 0;                 // 4096*2048
constexpr long long O_QSEG  = 8388608;           // 4096*2048
constexpr long long O_KSEG  = 16777216;          // 4096*256
constexpr long long O_VSEG  = 17825792;          // 4096*256
constexpr long long O_QF    = 18874368;          // 4096*2048 (roped, scaled)
constexpr long long O_KF    = 27262976;          // 4096*256
constexpr long long O_VF    = 28311552;          // 4096*256
constexpr long long O_VT    = 29360128;          // B*256*1024
constexpr long long O_ENC   = 30408704;          // 4096*2048
constexpr long long O_RESID = 38797312;          // 4096*2048
constexpr long long O_GATE  = 47185920;          // 3072*16384 (also logits 32M)
constexpr long long O_UP    = 97517568;          // 3072*16384
constexpr long long O_LOGIT = O_GATE;
constexpr long long O_HID   = O_PRE;

__device__ inline __bf16 f2bf(float f) {
    unsigned u = __builtin_bit_cast(unsigned, f);
    unsigned short h = (unsigned short)((u + 0x7fffu + ((u >> 16) & 1u)) >> 16);
    return __builtin_bit_cast(__bf16, h);
}

// ---------------------------------------------------------------------------
// General batched GEMM:  C[m][n] = sum_k A[m][k] * W[n][k]  (+ add)
// A fp32 (lda), W fp32 (ldb), C fp32 (ldc). bf16 MFMA, fp32 accumulate.
// Tiles: BM=BN=128, BK=32. 256 threads = 4 waves (2x2), 64x64 per wave.
// grid.z = batch1*batch2; pointer offsets via strides.
// ---------------------------------------------------------------------------
__global__ __launch_bounds__(256) void gemm_bt(
    const float* __restrict__ A, const float* __restrict__ Bw,
    float* __restrict__ C, const float* __restrict__ addp,
    int Kd, int lda, int ldb, int ldc,
    int batch2,
    long long sA1, long long sA2, long long sB1, long long sB2,
    long long sC1, long long sC2)
{
    const int z  = blockIdx.z;
    const int i1 = z / batch2, i2 = z % batch2;
    A  += i1 * sA1 + i2 * sA2;
    Bw += i1 * sB1 + i2 * sB2;
    const long long coff = i1 * sC1 + i2 * sC2;
    C += coff;
    if (addp) addp += coff;

    const int tid  = threadIdx.x;
    const int wave = tid >> 6, lane = tid & 63;
    const int waveM = wave & 1, waveN = wave >> 1;
    const int bm = blockIdx.y * 128, bn = blockIdx.x * 128;

    __shared__ __bf16 As[128][40];   // +8 pad: rows 80B apart -> 2-way (free)
    __shared__ __bf16 Bs[128][40];

    f32_4 acc[4][4] = {};

    const int sr = tid >> 3;        // 0..31
    const int sc = (tid & 7) * 4;   // 0,4,...,28
    const int fr = lane & 15, ko = (lane >> 4) * 8;

    for (int k0 = 0; k0 < Kd; k0 += 32) {
#pragma unroll
        for (int p = 0; p < 4; ++p) {
            int r = sr + 32 * p;
            float4 v = *(const float4*)(A + (long long)(bm + r) * lda + k0 + sc);
            __bf16* d = &As[r][sc];
            d[0] = f2bf(v.x); d[1] = f2bf(v.y); d[2] = f2bf(v.z); d[3] = f2bf(v.w);
        }
#pragma unroll
        for (int p = 0; p < 4; ++p) {
            int r = sr + 32 * p;
            float4 v = *(const float4*)(Bw + (long long)(bn + r) * ldb + k0 + sc);
            __bf16* d = &Bs[r][sc];
            d[0] = f2bf(v.x); d[1] = f2bf(v.y); d[2] = f2bf(v.z); d[3] = f2bf(v.w);
        }
        __syncthreads();

        bf16_8 af[4], bfr[4];
#pragma unroll
        for (int mt = 0; mt < 4; ++mt)
            af[mt] = *(const bf16_8*)&As[waveM * 64 + mt * 16 + fr][ko];
#pragma unroll
        for (int nt = 0; nt < 4; ++nt)
            bfr[nt] = *(const bf16_8*)&Bs[waveN * 64 + nt * 16 + fr][ko];
#pragma unroll
        for (int mt = 0; mt < 4; ++mt)
#pragma unroll
            for (int nt = 0; nt < 4; ++nt)
                acc[mt][nt] = __builtin_amdgcn_mfma_f32_16x16x32_bf16(
                    af[mt], bfr[nt], acc[mt][nt], 0, 0, 0);
        __syncthreads();
    }

    // Epilogue. C/D layout: col = lane&15, row = (lane>>4)*4 + reg.
    const int col0 = lane & 15, row0 = (lane >> 4) * 4;
#pragma unroll
    for (int mt = 0; mt < 4; ++mt) {
#pragma unroll
        for (int nt = 0; nt < 4; ++nt) {
            int row = bm + waveM * 64 + mt * 16 + row0;
            int col = bn + waveN * 64 + nt * 16 + col0;
#pragma unroll
            for (int r = 0; r < 4; ++r) {
                long long off = (long long)(row + r) * ldc + col;
                float v = acc[mt][nt][r];
                if (addp) v += addp[off];
                C[off] = v;
            }
        }
    }
}

// ---------------------------------------------------------------------------
// RMSNorm: one block per row of 2048. y = x * rsqrt(mean(x^2)+1e-6) * (1+scale)
// ---------------------------------------------------------------------------
__global__ __launch_bounds__(256) void rmsnorm_k(
    const float* __restrict__ x, const float* __restrict__ scale,
    float* __restrict__ y)
{
    const long long base = (long long)blockIdx.x * 2048;
    const int tid = threadIdx.x;
    float4 v0 = *(const float4*)(x + base + tid * 4);
    float4 v1 = *(const float4*)(x + base + 1024 + tid * 4);
    float ss = v0.x * v0.x + v0.y * v0.y + v0.z * v0.z + v0.w * v0.w
             + v1.x * v1.x + v1.y * v1.y + v1.z * v1.z + v1.w * v1.w;
#pragma unroll
    for (int o = 32; o > 0; o >>= 1) ss += __shfl_down(ss, o, 64);
    __shared__ float red[4];
    int lane = tid & 63, w = tid >> 6;
    if (lane == 0) red[w] = ss;
    __syncthreads();
    float tot = red[0] + red[1] + red[2] + red[3];
    float rs = rsqrtf(tot * (1.0f / 2048.0f) + 1e-6f);
    float4 s0 = *(const float4*)(scale + tid * 4);
    float4 s1 = *(const float4*)(scale + 1024 + tid * 4);
    float4 o0, o1;
    o0.x = v0.x * rs * (1.f + s0.x); o0.y = v0.y * rs * (1.f + s0.y);
    o0.z = v0.z * rs * (1.f + s0.z); o0.w = v0.w * rs * (1.f + s0.w);
    o1.x = v1.x * rs * (1.f + s1.x); o1.y = v1.y * rs * (1.f + s1.y);
    o1.z = v1.z * rs * (1.f + s1.z); o1.w = v1.w * rs * (1.f + s1.w);
    *(float4*)(y + base + tid * 4) = o0;
    *(float4*)(y + base + 1024 + tid * 4) = o1;
}

// ---------------------------------------------------------------------------
// RoPE + scatter segment rows into [B, T=1024, .] layout. q scaled by H^-0.5.
// One block per segment token.
// ---------------------------------------------------------------------------
__global__ __launch_bounds__(256) void rope_scatter(
    const float* __restrict__ qs, const float* __restrict__ ks,
    const float* __restrict__ vs, const int* __restrict__ posarr,
    float* __restrict__ qf, float* __restrict__ kf, float* __restrict__ vf,
    int Tseg, int Toff)
{
    const int rowseg = blockIdx.x;
    const int b = rowseg / Tseg, t = rowseg - b * Tseg;
    const int tg = Toff + t;
    const float fpos = (float)posarr[b * 1024 + tg];
    const float* q = qs + (long long)rowseg * 2048;
    const float* k = ks + (long long)rowseg * 256;
    const float* v = vs + (long long)rowseg * 256;
    const long long qbase = ((long long)b * 1024 + tg) * 2048;
    const long long kbase = ((long long)b * 1024 + tg) * 256;
    const int tid = threadIdx.x;

    for (int idx = tid; idx < 1024; idx += 256) {  // 8 heads x 128 pairs
        int h = idx >> 7, i = idx & 127;
        float ts = powf(10000.0f, (float)i * (1.0f / 128.0f));
        float rad = fpos / ts;
        float sn, cs; sincosf(rad, &sn, &cs);
        float x1 = q[h * 256 + i], x2 = q[h * 256 + i + 128];
        qf[qbase + h * 256 + i]       = (x1 * cs - x2 * sn) * 0.0625f;
        qf[qbase + h * 256 + i + 128] = (x2 * cs + x1 * sn) * 0.0625f;
    }
    if (tid < 128) {
        int i = tid;
        float ts = powf(10000.0f, (float)i * (1.0f / 128.0f));
        float rad = fpos / ts;
        float sn, cs; sincosf(rad, &sn, &cs);
        float x1 = k[i], x2 = k[i + 128];
        kf[kbase + i]       = x1 * cs - x2 * sn;
        kf[kbase + i + 128] = x2 * cs + x1 * sn;
    }
    vf[kbase + tid] = v[tid];
}

// ---------------------------------------------------------------------------
// V transpose: [B,1024,256] -> [B,256,1024]
// ---------------------------------------------------------------------------
__global__ __launch_bounds__(256) void vtrans_k(
    const float* __restrict__ vf, float* __restrict__ vt)
{
    long long idx = (long long)blockIdx.x * 256 + threadIdx.x;  // B*256*1024
    int s = (int)(idx & 1023);
    int h = (int)((idx >> 10) & 255);
    int b = (int)(idx >> 18);
    vt[idx] = vf[((long long)(b * 1024 + s)) * 256 + h];
}

// ---------------------------------------------------------------------------
// Masked softmax over s (1024) in-place. Row index = (b*8+n)*1024 + t.
// valid: s < T0(256)  OR  s <= t. Invalid entries set to 0.
// ---------------------------------------------------------------------------
__global__ __launch_bounds__(256) void softmax_mask(float* __restrict__ lg)
{
    const long long row = blockIdx.x;
    const int t = (int)(row & 1023);
    float* p = lg + row * 1024;
    const int vend = (t < 256) ? 256 : (t + 1);
    const int tid = threadIdx.x;
    const int lane = tid & 63, w = tid >> 6;

    float v[4];
    float mx = -3.4e38f;
#pragma unroll
    for (int j = 0; j < 4; ++j) {
        int i = tid + 256 * j;
        float x = p[i];
        v[j] = x;
        if (i < vend) mx = fmaxf(mx, x);
    }
#pragma unroll
    for (int o = 32; o > 0; o >>= 1) mx = fmaxf(mx, __shfl_down(mx, o, 64));
    __shared__ float redm[4], reds[4];
    if (lane == 0) redm[w] = mx;
    __syncthreads();
    float M = fmaxf(fmaxf(redm[0], redm[1]), fmaxf(redm[2], redm[3]));

    float s = 0.f;
#pragma unroll
    for (int j = 0; j < 4; ++j) {
        int i = tid + 256 * j;
        float e = (i < vend) ? __expf(v[j] - M) : 0.f;
        v[j] = e; s += e;
    }
#pragma unroll
    for (int o = 32; o > 0; o >>= 1) s += __shfl_down(s, o, 64);
    if (lane == 0) reds[w] = s;
    __syncthreads();
    float inv = 1.f / (reds[0] + reds[1] + reds[2] + reds[3]);
#pragma unroll
    for (int j = 0; j < 4; ++j) p[tid + 256 * j] = v[j] * inv;
}

// ---------------------------------------------------------------------------
// gelu(gate)*up, in-place into gate. float4 per thread.
// ---------------------------------------------------------------------------
__global__ __launch_bounds__(256) void gelu_mul(
    float4* __restrict__ g, const float4* __restrict__ u)
{
    long long i = (long long)blockIdx.x * 256 + threadIdx.x;
    float4 gv = g[i], uv = u[i];
    float4 r;
    {
        float x = gv.x; float tt = tanhf(0.7978845608028654f * (x + 0.044715f * x * x * x));
        r.x = 0.5f * x * (1.f + tt) * uv.x;
    }
    {
        float x = gv.y; float tt = tanhf(0.7978845608028654f * (x + 0.044715f * x * x * x));
        r.y = 0.5f * x * (1.f + tt) * uv.y;
    }
    {
        float x = gv.z; float tt = tanhf(0.7978845608028654f * (x + 0.044715f * x * x * x));
        r.z = 0.5f * x * (1.f + tt) * uv.z;
    }
    {
        float x = gv.w; float tt = tanhf(0.7978845608028654f * (x + 0.044715f * x * x * x));
        r.w = 0.5f * x * (1.f + tt) * uv.w;
    }
    g[i] = r;
}

// ---------------------------------------------------------------------------
// Launcher
// ---------------------------------------------------------------------------
extern "C" void kernel_launch(void* const* d_in, const int* in_sizes, int n_in,
                              void* d_out, int out_size, void* d_ws, size_t ws_size,
                              hipStream_t stream)
{
    const float* x0  = (const float*)d_in[0];
    const float* x1  = (const float*)d_in[1];
    const int*   pos = (const int*)d_in[2];
    const float* qw[2] = {(const float*)d_in[4],  (const float*)d_in[13]};
    const float* kw[2] = {(const float*)d_in[5],  (const float*)d_in[14]};
    const float* vw[2] = {(const float*)d_in[6],  (const float*)d_in[15]};
    const float* ow[2] = {(const float*)d_in[7],  (const float*)d_in[16]};
    const float* gw[2] = {(const float*)d_in[8],  (const float*)d_in[17]};
    const float* uw[2] = {(const float*)d_in[9],  (const float*)d_in[18]};
    const float* dw[2] = {(const float*)d_in[10], (const float*)d_in[19]};
    const float* pa[2] = {(const float*)d_in[11], (const float*)d_in[20]};
    const float* pf[2] = {(const float*)d_in[12], (const float*)d_in[21]};
    float* ws  = (float*)d_ws;
    float* out = (float*)d_out;

    auto gemm = [&](const float* A, const float* Bw, float* C, const float* addp,
                    int M, int N, int Kd, int lda, int ldb, int ldc,
                    int b1, int b2,
                    long long sA1, long long sA2, long long sB1, long long sB2,
                    long long sC1, long long sC2) {
        dim3 g(N / 128, M / 128, b1 * b2);
        gemm_bt<<<g, 256, 0, stream>>>(A, Bw, C, addp, Kd, lda, ldb, ldc, b2,
                                       sA1, sA2, sB1, sB2, sC1, sC2);
    };

    float* pre   = ws + O_PRE;
    float* qseg  = ws + O_QSEG;
    float* kseg  = ws + O_KSEG;
    float* vseg  = ws + O_VSEG;
    float* qf    = ws + O_QF;
    float* kf    = ws + O_KF;
    float* vf    = ws + O_VF;
    float* vt    = ws + O_VT;
    float* enc   = ws + O_ENC;
    float* resid = ws + O_RESID;
    float* gate  = ws + O_GATE;
    float* up    = ws + O_UP;
    float* logit = ws + O_LOGIT;
    float* hid   = ws + O_HID;

    // 1. pre-attn RMSNorm (segment-contiguous)
    rmsnorm_k<<<1024, 256, 0, stream>>>(x0, pa[0], pre);
    rmsnorm_k<<<3072, 256, 0, stream>>>(x1, pa[1], pre + 1024LL * 2048);

    // 2. QKV projections (per segment)
    gemm(pre,                 qw[0], qseg,                 nullptr, 1024, 2048, 2048, 2048, 2048, 2048, 1, 1, 0,0,0,0,0,0);
    gemm(pre + 1024LL * 2048, qw[1], qseg + 1024LL * 2048, nullptr, 3072, 2048, 2048, 2048, 2048, 2048, 1, 1, 0,0,0,0,0,0);
    gemm(pre,                 kw[0], kseg,                 nullptr, 1024,  256, 2048, 2048, 2048,  256, 1, 1, 0,0,0,0,0,0);
    gemm(pre + 1024LL * 2048, kw[1], kseg + 1024LL * 256,  nullptr, 3072,  256, 2048, 2048, 2048,  256, 1, 1, 0,0,0,0,0,0);
    gemm(pre,                 vw[0], vseg,                 nullptr, 1024,  256, 2048, 2048, 2048,  256, 1, 1, 0,0,0,0,0,0);
    gemm(pre + 1024LL * 2048, vw[1], vseg + 1024LL * 256,  nullptr, 3072,  256, 2048, 2048, 2048,  256, 1, 1, 0,0,0,0,0,0);

    // 3. RoPE + scatter into [B,1024,.] (q scaled by 1/16)
    rope_scatter<<<1024, 256, 0, stream>>>(qseg, kseg, vseg, pos, qf, kf, vf, 256, 0);
    rope_scatter<<<3072, 256, 0, stream>>>(qseg + 1024LL * 2048, kseg + 1024LL * 256,
                                           vseg + 1024LL * 256, pos, qf, kf, vf, 768, 256);

    // 4. V transpose
    vtrans_k<<<4096, 256, 0, stream>>>(vf, vt);

    // 5. logits[b][n][t][s] = q[b,t,n,:] . k[b,s,:]   (batch1=B, batch2=8 heads)
    gemm(qf, kf, logit, nullptr, 1024, 1024, 256, 2048, 256, 1024,
         4, 8,
         1024LL * 2048, 256,          // A: batch b, head n
         1024LL * 256, 0,             // B: batch b
         8LL * 1024 * 1024, 1024LL * 1024);

    // 6. masked softmax (in-place)
    softmax_mask<<<32768, 256, 0, stream>>>(logit);

    // 7. enc[b][t][n*256+h] = probs . V
    gemm(logit, vt, enc, nullptr, 1024, 256, 1024, 1024, 1024, 2048,
         4, 8,
         8LL * 1024 * 1024, 1024LL * 1024,
         256LL * 1024, 0,
         1024LL * 2048, 256);

    // 8. O-proj + residual (fused add)
    gemm(enc, ow[0], resid, x0, 256, 2048, 2048, 2048, 2048, 2048,
         4, 1, 1024LL * 2048, 0, 0, 0, 256LL * 2048, 0);
    gemm(enc + 256LL * 2048, ow[1], resid + 1024LL * 2048, x1, 768, 2048, 2048, 2048, 2048, 2048,
         4, 1, 1024LL * 2048, 0, 0, 0, 768LL * 2048, 0);

    // 9. MLP per segment (sequential; reuse gate/up buffers)
    for (int s = 0; s < 2; ++s) {
        int Ms = s ? 3072 : 1024;
        float* rs = resid + (s ? 1024LL * 2048 : 0);
        float* os = out + (s ? 1024LL * 2048 : 0);
        rmsnorm_k<<<Ms, 256, 0, stream>>>(rs, pf[s], hid);
        gemm(hid, gw[s], gate, nullptr, Ms, 16384, 2048, 2048, 2048, 16384, 1, 1, 0,0,0,0,0,0);
        gemm(hid, uw[s], up,   nullptr, Ms, 16384, 2048, 2048, 2048, 16384, 1, 1, 0,0,0,0,0,0);
        gelu_mul<<<(Ms * 16384) / 1024, 256, 0, stream>>>((float4*)gate, (const float4*)up);
        gemm(gate, dw[s], os, rs, Ms, 2048, 16384, 16384, 16384, 2048, 1, 1, 0,0,0,0,0,0);
    }
}